// Round 8
// baseline (221.609 us; speedup 1.0000x reference)
//
#include <hip/hip_runtime.h>
#include <hip/hip_fp16.h>
#include <stdint.h>

#define NROWS 8192   // B*S
#define HDIM  128
#define KSUB  8
#define NC    4096
#define DSUB  16
#define OUTD  6

#define FB_TAU 4e-3f                // fallback margin; >> worst-case split-fp16 error (~3e-4)
#define DOTSCALE (-2.0f / 4096.0f)  // undo x*256, c*16 scaling; exact pow2

typedef _Float16 f16x8 __attribute__((ext_vector_type(8)));
typedef float    f32x4 __attribute__((ext_vector_type(4)));

// ws layout (bytes): total 8,519,680 (< round-6's proven 9,043,968)
#define XK_OFF 0u            // xk:   [KSUB][NROWS][DSUB] fp32, 4 MiB
#define CN_OFF 4194304u      // cnorm:[KSUB][NC] fp32, 128 KiB
#define B1_OFF 4325376u      // B1S:  [KSUB][256 tiles][64 lanes] f16x8, 2 MiB
#define PK_OFF 6422528u      // pk:   [4 splits][NROWS][KSUB] u64, 2 MiB

// ---------------- Kernel 1: prep = bprep (blocks 0..511) + MLP/cnorm (512..767) --------
__global__ __launch_bounds__(256) void prep_kernel(
    const float* __restrict__ z, const float* __restrict__ W1, const float* __restrict__ b1,
    const float* __restrict__ W2, const float* __restrict__ b2,
    const float* __restrict__ ce,
    float* __restrict__ xk, float* __restrict__ cnorm, f16x8* __restrict__ B1S)
{
    __shared__ float h1s[32 * HDIM];    // 16 KiB
    __shared__ float w2s[HDIM * HDIM];  // 64 KiB
    const int t = threadIdx.x;

    if (blockIdx.x < 512) {
        // ---- bprep: fp16 hi/lo centroid B-fragments (B2 = B1[lane^32]) ----
        const int e = blockIdx.x * 256 + t;              // 0..131071
        const int k    = e >> 14;
        const int tile = (e >> 6) & 255;
        const int lane = e & 63;
        const int col  = lane & 15;
        const int quad = lane >> 4;
        const int dims = (quad & 1) * 8;
        const int part = quad >> 1;                      // 0: hi half of K, 1: lo half
        const int n = tile * 16 + col;
        const float* cp = &ce[((size_t)k * NC + n) * DSUB + dims];
        f16x8 hi, lo;
        #pragma unroll
        for (int j = 0; j < 8; ++j) {
            const float s = cp[j] * 16.0f;               // pow2 scale keeps lo normal
            const _Float16 h = (_Float16)s;
            hi[j] = h;
            lo[j] = (_Float16)(s - (float)h);
        }
        B1S[e] = part ? lo : hi;
        return;
    }

    // ---- MLP ----
    const int bx = blockIdx.x - 512;                     // 0..255
    const int row0 = bx * 32;

    // centroid norms (first 128 mlp-blocks cover KSUB*NC = 32768 centroids)
    if (bx < (KSUB * NC) / 256) {
        const int g = bx * 256 + t;
        const float4* cp = (const float4*)&ce[(size_t)g * DSUB];
        float nn = 0.f;
        #pragma unroll
        for (int q = 0; q < 4; ++q) {
            const float4 v = cp[q];
            nn = fmaf(v.x, v.x, nn); nn = fmaf(v.y, v.y, nn);
            nn = fmaf(v.z, v.z, nn); nn = fmaf(v.w, v.w, nn);
        }
        cnorm[g] = nn;
    }

    // stage W2 (coalesced)
    {
        const float4* g4 = (const float4*)W2;
        float4* s4 = (float4*)w2s;
        #pragma unroll
        for (int q = 0; q < 16; ++q) s4[t + q * 256] = g4[t + q * 256];
    }

    // phase A: h1 = relu(z @ W1 + b1) into LDS (32x128)
    #pragma unroll
    for (int e = 0; e < 16; ++e) {
        const int idx = e * 256 + t;
        const int r = idx >> 7, j = idx & 127;
        const int n = row0 + r;
        float acc = b1[j];
        acc = fmaf(z[n * 3 + 0], W1[0 * HDIM + j], acc);
        acc = fmaf(z[n * 3 + 1], W1[1 * HDIM + j], acc);
        acc = fmaf(z[n * 3 + 2], W1[2 * HDIM + j], acc);
        h1s[idx] = fmaxf(acc, 0.f);
    }
    __syncthreads();

    // phase B: 4 rows x 4 cols per thread
    const int c4 = (t & 31) * 4;
    const int r4 = (t >> 5) * 4;
    float acc[4][4];
    #pragma unroll
    for (int a = 0; a < 4; ++a)
        #pragma unroll
        for (int b = 0; b < 4; ++b) acc[a][b] = 0.f;

    for (int k4 = 0; k4 < HDIM; k4 += 4) {
        float hh[4][4], ww[4][4];
        #pragma unroll
        for (int q = 0; q < 4; ++q) {
            const float4 v = *(const float4*)&h1s[(r4 + q) * HDIM + k4];
            hh[q][0] = v.x; hh[q][1] = v.y; hh[q][2] = v.z; hh[q][3] = v.w;
        }
        #pragma unroll
        for (int p = 0; p < 4; ++p) {
            const float4 v = *(const float4*)&w2s[(k4 + p) * HDIM + c4];
            ww[p][0] = v.x; ww[p][1] = v.y; ww[p][2] = v.z; ww[p][3] = v.w;
        }
        #pragma unroll
        for (int q = 0; q < 4; ++q)
            #pragma unroll
            for (int p = 0; p < 4; ++p) {
                acc[q][0] = fmaf(hh[q][p], ww[p][0], acc[q][0]);
                acc[q][1] = fmaf(hh[q][p], ww[p][1], acc[q][1]);
                acc[q][2] = fmaf(hh[q][p], ww[p][2], acc[q][2]);
                acc[q][3] = fmaf(hh[q][p], ww[p][3], acc[q][3]);
            }
    }

    const float4 bb = *(const float4*)&b2[c4];
    const int kk = c4 >> 4;
    const int dd = c4 & 15;
    #pragma unroll
    for (int q = 0; q < 4; ++q) {
        float4 o;
        o.x = fmaxf(acc[q][0] + bb.x, 0.f);
        o.y = fmaxf(acc[q][1] + bb.y, 0.f);
        o.z = fmaxf(acc[q][2] + bb.z, 0.f);
        o.w = fmaxf(acc[q][3] + bb.w, 0.f);
        *(float4*)&xk[((size_t)kk * NROWS + (row0 + r4 + q)) * DSUB + dd] = o;
    }
}

// ---------------- Kernel 2: MFMA argmin, LDS-staged ----------------
// grid (64, 8 k, 4 csplit) = 2048 blocks. Block = 4 same-(k,cz) waves sharing a
// 16-tile LDS chunk (kills the redundant per-wave global B1 stream that capped
// round 7 at 60% VALUBusy / ~20 TB/s L2 demand). Chained MFMA pairs, norms in
// registers per chunk. Output: packed u64 okey(m1)<<32 | f16(m2-m1)<<16 | idx.
__global__ __launch_bounds__(256, 4) void argmin_kernel(
    const float* __restrict__ xk, const f16x8* __restrict__ B1S,
    const float* __restrict__ cnorm, unsigned long long* __restrict__ pk)
{
    __shared__ f16x8 cs[16 * 64];   // 16 KiB = 16 tiles
    const int t = threadIdx.x;
    const int lane = t & 63;
    const int wid  = t >> 6;
    const int k  = blockIdx.y;                 // 0..7
    const int cz = blockIdx.z;                 // 0..3
    const int rb = blockIdx.x * 4 + wid;       // 0..255 (32-row block)
    const int col  = lane & 15;
    const int quad = lane >> 4;
    const int dims = (quad & 1) * 8;
    const int part = quad >> 1;

    // A fragments for 2 groups of 16 rows (hi/lo split, exact)
    f16x8 A[2];
    #pragma unroll
    for (int g = 0; g < 2; ++g) {
        const int row = rb * 32 + g * 16 + col;
        const float* xp = &xk[((size_t)k * NROWS + row) * DSUB + dims];
        f16x8 hi, lo;
        #pragma unroll
        for (int j = 0; j < 8; ++j) {
            const float s = xp[j] * 256.0f;
            const _Float16 h = (_Float16)s;
            hi[j] = h;
            lo[j] = (_Float16)(s - (float)h);
        }
        A[g] = part ? lo : hi;
    }

    float m1[2][4], m2[2][4];
    int   idx[2][4];
    #pragma unroll
    for (int g = 0; g < 2; ++g)
        #pragma unroll
        for (int j = 0; j < 4; ++j) { m1[g][j] = 1e30f; m2[g][j] = 1e30f; idx[g][j] = 0; }

    const f16x8* gp  = &B1S[((size_t)k * 256 + cz * 64) * 64];
    const float* cnp = &cnorm[k * NC + cz * 64 * 16 + col];

    for (int ch = 0; ch < 4; ++ch) {
        __syncthreads();                       // previous chunk consumed
        {   // stage 16 tiles (16 KiB), all 4 waves cooperate, coalesced
            const uint4* g4 = (const uint4*)(gp + (size_t)ch * 1024);
            uint4* s4 = (uint4*)cs;
            #pragma unroll
            for (int q = 0; q < 4; ++q) s4[t + q * 256] = g4[t + q * 256];
        }
        // chunk norms -> registers (global, L2-hot; keeps them off the LDS pipe)
        float nr[16];
        #pragma unroll
        for (int tt = 0; tt < 16; ++tt) nr[tt] = cnp[(ch * 16 + tt) * 16];
        __syncthreads();

        #pragma unroll
        for (int tt = 0; tt < 16; ++tt) {
            const f16x8 b1 = cs[tt * 64 + lane];
            const f16x8 b2 = cs[tt * 64 + (lane ^ 32)];   // part-flipped partner
            const f32x4 zz = {0.f, 0.f, 0.f, 0.f};
            f32x4 p0 = __builtin_amdgcn_mfma_f32_16x16x32_f16(A[0], b1, zz, 0, 0, 0);
            p0       = __builtin_amdgcn_mfma_f32_16x16x32_f16(A[0], b2, p0, 0, 0, 0);
            f32x4 p1 = __builtin_amdgcn_mfma_f32_16x16x32_f16(A[1], b1, zz, 0, 0, 0);
            p1       = __builtin_amdgcn_mfma_f32_16x16x32_f16(A[1], b2, p1, 0, 0, 0);
            const int c = ((cz * 64 + ch * 16 + tt) << 4) + col;
            #pragma unroll
            for (int j = 0; j < 4; ++j) {
                {
                    const float s = fmaf(p0[j], DOTSCALE, nr[tt]);
                    const bool lt = s < m1[0][j];
                    m2[0][j] = __builtin_amdgcn_fmed3f(s, m1[0][j], m2[0][j]);
                    idx[0][j] = lt ? c : idx[0][j];
                    m1[0][j] = fminf(s, m1[0][j]);
                }
                {
                    const float s = fmaf(p1[j], DOTSCALE, nr[tt]);
                    const bool lt = s < m1[1][j];
                    m2[1][j] = __builtin_amdgcn_fmed3f(s, m1[1][j], m2[1][j]);
                    idx[1][j] = lt ? c : idx[1][j];
                    m1[1][j] = fminf(s, m1[1][j]);
                }
            }
        }
    }

    // reduce across the 16 lanes of each quad
    #pragma unroll
    for (int off = 1; off < 16; off <<= 1) {
        #pragma unroll
        for (int g = 0; g < 2; ++g)
            #pragma unroll
            for (int j = 0; j < 4; ++j) {
                const float om1 = __shfl_xor(m1[g][j], off, 64);
                const float om2 = __shfl_xor(m2[g][j], off, 64);
                const int  oidx = __shfl_xor(idx[g][j], off, 64);
                const bool better = (om1 < m1[g][j]) ||
                                    (om1 == m1[g][j] && oidx < idx[g][j]);
                m2[g][j] = fminf(fminf(m2[g][j], om2), fmaxf(m1[g][j], om1));
                m1[g][j] = better ? om1 : m1[g][j];
                idx[g][j] = better ? oidx : idx[g][j];
            }
    }

    if (col == 0) {
        #pragma unroll
        for (int g = 0; g < 2; ++g)
            #pragma unroll
            for (int j = 0; j < 4; ++j) {
                const int row = rb * 32 + g * 16 + quad * 4 + j;
                unsigned u = __float_as_uint(m1[g][j]);
                u = (u & 0x80000000u) ? ~u : (u | 0x80000000u);      // order-preserving
                const unsigned short dh =
                    __half_as_ushort(__float2half(m2[g][j] - m1[g][j]));
                pk[((size_t)cz * NROWS + row) * KSUB + k] =
                    ((unsigned long long)u << 32) |
                    ((unsigned)dh << 16) | (unsigned)idx[g][j];
            }
    }
}

// ---------------- Kernel 3: finish = merge + exact rescue + LUT output ----------------
// Row-partitioned: block owns 32 rows; all merge/rescue/out deps are block-local
// (codes + worklist in LDS). No global codes array, no atomics on global.
__global__ __launch_bounds__(256) void finish_kernel(
    const float* __restrict__ xk, const float* __restrict__ ce,
    const float* __restrict__ cnorm, const unsigned long long* __restrict__ pk,
    const float* __restrict__ W3, const float* __restrict__ b3,
    float* __restrict__ out)
{
    __shared__ int codes_s[256];
    __shared__ int wl_s[256];
    __shared__ int wcnt;
    const int t = threadIdx.x;
    const int row0 = blockIdx.x * 32;
    if (t == 0) wcnt = 0;
    __syncthreads();

    // merge 4 splits for (row, k) = (row0 + t>>3, t&7)
    {
        const int row = row0 + (t >> 3);
        const int k = t & 7;
        unsigned long long p[4];
        #pragma unroll
        for (int s = 0; s < 4; ++s)
            p[s] = pk[((size_t)s * NROWS + row) * KSUB + k];
        unsigned long long w = p[0];
        #pragma unroll
        for (int s = 1; s < 4; ++s) w = p[s] < w ? p[s] : w;
        const unsigned uw = (unsigned)(w >> 32);
        const float m1w = __uint_as_float((uw & 0x80000000u) ? (uw ^ 0x80000000u) : ~uw);
        float m2g = m1w + (float)__ushort_as_half((unsigned short)((unsigned)w >> 16));
        #pragma unroll
        for (int s = 0; s < 4; ++s) {
            if (p[s] != w) {   // splits have disjoint idx ranges -> pk values unique
                const unsigned us = (unsigned)(p[s] >> 32);
                m2g = fminf(m2g, __uint_as_float(
                    (us & 0x80000000u) ? (us ^ 0x80000000u) : ~us));
            }
        }
        codes_s[t] = (int)(w & 0xFFFFull);
        if (m2g - m1w < FB_TAU) {      // near-tie: exact fp32 rescan needed
            const int slot = atomicAdd(&wcnt, 1);
            wl_s[slot] = t;
        }
    }
    __syncthreads();

    // exact fp32 rescue, wave-per-item over the block-local worklist
    {
        const int lane = t & 63;
        const int wid = t >> 6;
        const int nitems = wcnt;
        for (int i = wid; i < nitems; i += 4) {
            const int wg = wl_s[i];
            const int row = row0 + (wg >> 3), k = wg & 7;
            float xr[DSUB];
            {
                const float* xp = &xk[((size_t)k * NROWS + row) * DSUB];
                #pragma unroll
                for (int q = 0; q < DSUB; q += 4) {
                    const float4 v = *(const float4*)&xp[q];
                    xr[q + 0] = -2.f * v.x; xr[q + 1] = -2.f * v.y;
                    xr[q + 2] = -2.f * v.z; xr[q + 3] = -2.f * v.w;
                }
            }
            float bm = 1e30f; int bi = NC;
            for (int c = lane; c < NC; c += 64) {
                const float* cp = &ce[((size_t)k * NC + c) * DSUB];
                float s = cnorm[k * NC + c];
                #pragma unroll
                for (int d = 0; d < DSUB; ++d) s = fmaf(xr[d], cp[d], s);
                if (s < bm) { bm = s; bi = c; }
            }
            #pragma unroll
            for (int off = 1; off < 64; off <<= 1) {
                const float om = __shfl_xor(bm, off, 64);
                const int  oi = __shfl_xor(bi, off, 64);
                const bool better = (om < bm) || (om == bm && oi < bi);
                bm = better ? om : bm;
                bi = better ? oi : bi;
            }
            if (lane == 0) codes_s[wg] = bi;
        }
    }
    __syncthreads();

    // output: 32 rows x 6 = 192 outputs
    if (t < 32 * OUTD) {
        const int nl = t / OUTD;
        const int o = t - nl * OUTD;
        const int n = row0 + nl;
        float acc = b3[o];
        #pragma unroll
        for (int k = 0; k < KSUB; ++k) {
            const int code = codes_s[nl * KSUB + k];
            const float* cp = &ce[((size_t)k * NC + code) * DSUB];
            const float* wp = &W3[(k * DSUB) * OUTD + o];
            #pragma unroll
            for (int d = 0; d < DSUB; ++d)
                acc = fmaf(cp[d], wp[d * OUTD], acc);
        }
        out[n * OUTD + o] = acc;
    }
}

extern "C" void kernel_launch(void* const* d_in, const int* in_sizes, int n_in,
                              void* d_out, int out_size, void* d_ws, size_t ws_size,
                              hipStream_t stream)
{
    const float* z  = (const float*)d_in[0];
    const float* W1 = (const float*)d_in[1];
    const float* b1 = (const float*)d_in[2];
    const float* W2 = (const float*)d_in[3];
    const float* b2 = (const float*)d_in[4];
    const float* ce = (const float*)d_in[5];
    const float* W3 = (const float*)d_in[6];
    const float* b3 = (const float*)d_in[7];

    char* ws = (char*)d_ws;
    float* xk    = (float*)(ws + XK_OFF);
    float* cnorm = (float*)(ws + CN_OFF);
    f16x8* B1S   = (f16x8*)(ws + B1_OFF);
    unsigned long long* pk = (unsigned long long*)(ws + PK_OFF);

    hipLaunchKernelGGL(prep_kernel, dim3(768), dim3(256), 0, stream,
                       z, W1, b1, W2, b2, ce, xk, cnorm, B1S);
    hipLaunchKernelGGL(argmin_kernel, dim3(64, 8, 4), dim3(256), 0, stream,
                       xk, B1S, cnorm, pk);
    hipLaunchKernelGGL(finish_kernel, dim3(256), dim3(256), 0, stream,
                       xk, ce, cnorm, pk, W3, b3, (float*)d_out);
}

// Round 9
// 170.419 us; speedup vs baseline: 1.3004x; 1.3004x over previous
//
#include <hip/hip_runtime.h>
#include <hip/hip_fp16.h>
#include <stdint.h>

#define NROWS 8192   // B*S
#define HDIM  128
#define KSUB  8
#define NC    4096
#define DSUB  16
#define OUTD  6

#define FB_TAU 3e-4f                // fallback margin; split-fp16 distance error bound ~4e-5
#define DOTSCALE (-2.0f / 4096.0f)  // undo x*256, c*16 scaling; exact pow2

typedef _Float16 f16x8 __attribute__((ext_vector_type(8)));
typedef float    f32x4 __attribute__((ext_vector_type(4)));

// ws layout (bytes): total 8,519,680
#define XK_OFF 0u            // xk:   [KSUB][NROWS][DSUB] fp32, 4 MiB
#define CN_OFF 4194304u      // cnorm:[KSUB][NC] fp32, 128 KiB
#define B1_OFF 4325376u      // B1S:  [KSUB][256 tiles][64 lanes] f16x8, 2 MiB
#define PK_OFF 6422528u      // pk:   [4 splits][NROWS][KSUB] u64, 2 MiB

// ---------------- Kernel 1: prep = MLP + cnorm + bprep (256 blocks) ----------------
__global__ __launch_bounds__(256) void prep_kernel(
    const float* __restrict__ z, const float* __restrict__ W1, const float* __restrict__ b1,
    const float* __restrict__ W2, const float* __restrict__ b2,
    const float* __restrict__ ce,
    float* __restrict__ xk, float* __restrict__ cnorm, f16x8* __restrict__ B1S)
{
    __shared__ float h1s[32 * HDIM];    // 16 KiB
    __shared__ float w2s[HDIM * HDIM];  // 64 KiB
    const int t = threadIdx.x;
    const int row0 = blockIdx.x * 32;

    // ---- bprep: 2 fragments per thread (256 blocks x 512 = 131072 entries) ----
    #pragma unroll
    for (int q = 0; q < 2; ++q) {
        const int e = blockIdx.x * 512 + q * 256 + t;    // (k, tile, lane)
        const int k    = e >> 14;
        const int tile = (e >> 6) & 255;
        const int lane = e & 63;
        const int col  = lane & 15;
        const int quad = lane >> 4;
        const int dims = (quad & 1) * 8;
        const int part = quad >> 1;                      // 0: hi half of K, 1: lo half
        const int n = tile * 16 + col;
        const float* cp = &ce[((size_t)k * NC + n) * DSUB + dims];
        f16x8 hi, lo;
        #pragma unroll
        for (int j = 0; j < 8; ++j) {
            const float s = cp[j] * 16.0f;               // pow2 scale keeps lo normal
            const _Float16 h = (_Float16)s;
            hi[j] = h;
            lo[j] = (_Float16)(s - (float)h);
        }
        B1S[e] = part ? lo : hi;
    }

    // centroid norms (first 128 blocks cover KSUB*NC = 32768 centroids)
    if (blockIdx.x < (KSUB * NC) / 256) {
        const int g = blockIdx.x * 256 + t;
        const float4* cp = (const float4*)&ce[(size_t)g * DSUB];
        float nn = 0.f;
        #pragma unroll
        for (int q = 0; q < 4; ++q) {
            const float4 v = cp[q];
            nn = fmaf(v.x, v.x, nn); nn = fmaf(v.y, v.y, nn);
            nn = fmaf(v.z, v.z, nn); nn = fmaf(v.w, v.w, nn);
        }
        cnorm[g] = nn;
    }

    // stage W2 (coalesced)
    {
        const float4* g4 = (const float4*)W2;
        float4* s4 = (float4*)w2s;
        #pragma unroll
        for (int q = 0; q < 16; ++q) s4[t + q * 256] = g4[t + q * 256];
    }

    // phase A: h1 = relu(z @ W1 + b1) into LDS (32x128)
    #pragma unroll
    for (int e = 0; e < 16; ++e) {
        const int idx = e * 256 + t;
        const int r = idx >> 7, j = idx & 127;
        const int n = row0 + r;
        float acc = b1[j];
        acc = fmaf(z[n * 3 + 0], W1[0 * HDIM + j], acc);
        acc = fmaf(z[n * 3 + 1], W1[1 * HDIM + j], acc);
        acc = fmaf(z[n * 3 + 2], W1[2 * HDIM + j], acc);
        h1s[idx] = fmaxf(acc, 0.f);
    }
    __syncthreads();

    // phase B: 4 rows x 4 cols per thread
    const int c4 = (t & 31) * 4;
    const int r4 = (t >> 5) * 4;
    float acc[4][4];
    #pragma unroll
    for (int a = 0; a < 4; ++a)
        #pragma unroll
        for (int b = 0; b < 4; ++b) acc[a][b] = 0.f;

    for (int k4 = 0; k4 < HDIM; k4 += 4) {
        float hh[4][4], ww[4][4];
        #pragma unroll
        for (int q = 0; q < 4; ++q) {
            const float4 v = *(const float4*)&h1s[(r4 + q) * HDIM + k4];
            hh[q][0] = v.x; hh[q][1] = v.y; hh[q][2] = v.z; hh[q][3] = v.w;
        }
        #pragma unroll
        for (int p = 0; p < 4; ++p) {
            const float4 v = *(const float4*)&w2s[(k4 + p) * HDIM + c4];
            ww[p][0] = v.x; ww[p][1] = v.y; ww[p][2] = v.z; ww[p][3] = v.w;
        }
        #pragma unroll
        for (int q = 0; q < 4; ++q)
            #pragma unroll
            for (int p = 0; p < 4; ++p) {
                acc[q][0] = fmaf(hh[q][p], ww[p][0], acc[q][0]);
                acc[q][1] = fmaf(hh[q][p], ww[p][1], acc[q][1]);
                acc[q][2] = fmaf(hh[q][p], ww[p][2], acc[q][2]);
                acc[q][3] = fmaf(hh[q][p], ww[p][3], acc[q][3]);
            }
    }

    const float4 bb = *(const float4*)&b2[c4];
    const int kk = c4 >> 4;
    const int dd = c4 & 15;
    #pragma unroll
    for (int q = 0; q < 4; ++q) {
        float4 o;
        o.x = fmaxf(acc[q][0] + bb.x, 0.f);
        o.y = fmaxf(acc[q][1] + bb.y, 0.f);
        o.z = fmaxf(acc[q][2] + bb.z, 0.f);
        o.w = fmaxf(acc[q][3] + bb.w, 0.f);
        *(float4*)&xk[((size_t)kk * NROWS + (row0 + r4 + q)) * DSUB + dd] = o;
    }
}

// ---------------- Kernel 2: MFMA argmin, LDS-staged, spill-free ----------------
// grid (64, 8 k, 4 cz) = 2048 blocks; 4 waves share 16-tile LDS chunks.
// Round-8 lesson: the per-thread nr[16] array + full unroll spilled to scratch
// (245 MB HBM writes). Fix: norms live in a 4 KiB LDS array staged once
// (broadcast reads), tile loop unrolled only 2x. Register budget ~70 VGPR.
__global__ __launch_bounds__(256, 4) void argmin_kernel(
    const float* __restrict__ xk, const f16x8* __restrict__ B1S,
    const float* __restrict__ cnorm, unsigned long long* __restrict__ pk)
{
    __shared__ f16x8 cs[16 * 64];   // 16 KiB = 16 tiles
    __shared__ float cnL[1024];     // 4 KiB  = norms for this (k, cz)
    const int t = threadIdx.x;
    const int lane = t & 63;
    const int wid  = t >> 6;
    const int k  = blockIdx.y;                 // 0..7
    const int cz = blockIdx.z;                 // 0..3
    const int rb = blockIdx.x * 4 + wid;       // 0..255 (32-row block)
    const int col  = lane & 15;
    const int quad = lane >> 4;
    const int dims = (quad & 1) * 8;
    const int part = quad >> 1;

    // stage the 1024 norms of this centroid split (once)
    {
        const float* cnp0 = &cnorm[k * NC + cz * 1024];
        #pragma unroll
        for (int q = 0; q < 4; ++q) cnL[t + q * 256] = cnp0[t + q * 256];
    }

    // A fragments for 2 groups of 16 rows (hi/lo split, exact)
    f16x8 A[2];
    #pragma unroll
    for (int g = 0; g < 2; ++g) {
        const int row = rb * 32 + g * 16 + col;
        const float* xp = &xk[((size_t)k * NROWS + row) * DSUB + dims];
        f16x8 hi, lo;
        #pragma unroll
        for (int j = 0; j < 8; ++j) {
            const float s = xp[j] * 256.0f;
            const _Float16 h = (_Float16)s;
            hi[j] = h;
            lo[j] = (_Float16)(s - (float)h);
        }
        A[g] = part ? lo : hi;
    }

    float m1[2][4], m2[2][4];
    int   idx[2][4];
    #pragma unroll
    for (int g = 0; g < 2; ++g)
        #pragma unroll
        for (int j = 0; j < 4; ++j) { m1[g][j] = 1e30f; m2[g][j] = 1e30f; idx[g][j] = 0; }

    const f16x8* gp = &B1S[((size_t)k * 256 + cz * 64) * 64];

    for (int ch = 0; ch < 4; ++ch) {
        __syncthreads();                       // previous chunk consumed (covers cnL 1st iter)
        {   // stage 16 tiles (16 KiB), all 4 waves cooperate, coalesced
            const uint4* g4 = (const uint4*)(gp + (size_t)ch * 1024);
            uint4* s4 = (uint4*)cs;
            #pragma unroll
            for (int q = 0; q < 4; ++q) s4[t + q * 256] = g4[t + q * 256];
        }
        __syncthreads();

        #pragma unroll 2
        for (int tt = 0; tt < 16; ++tt) {
            const f16x8 b1 = cs[tt * 64 + lane];
            const f16x8 b2 = cs[tt * 64 + (lane ^ 32)];   // part-flipped partner
            const float nrm = cnL[(ch * 16 + tt) * 16 + col];  // 16 words, broadcast
            const f32x4 zz = {0.f, 0.f, 0.f, 0.f};
            f32x4 p0 = __builtin_amdgcn_mfma_f32_16x16x32_f16(A[0], b1, zz, 0, 0, 0);
            p0       = __builtin_amdgcn_mfma_f32_16x16x32_f16(A[0], b2, p0, 0, 0, 0);
            f32x4 p1 = __builtin_amdgcn_mfma_f32_16x16x32_f16(A[1], b1, zz, 0, 0, 0);
            p1       = __builtin_amdgcn_mfma_f32_16x16x32_f16(A[1], b2, p1, 0, 0, 0);
            const int c = ((cz * 64 + ch * 16 + tt) << 4) + col;
            #pragma unroll
            for (int j = 0; j < 4; ++j) {
                {
                    const float s = fmaf(p0[j], DOTSCALE, nrm);
                    const bool lt = s < m1[0][j];
                    m2[0][j] = __builtin_amdgcn_fmed3f(s, m1[0][j], m2[0][j]);
                    idx[0][j] = lt ? c : idx[0][j];
                    m1[0][j] = fminf(s, m1[0][j]);
                }
                {
                    const float s = fmaf(p1[j], DOTSCALE, nrm);
                    const bool lt = s < m1[1][j];
                    m2[1][j] = __builtin_amdgcn_fmed3f(s, m1[1][j], m2[1][j]);
                    idx[1][j] = lt ? c : idx[1][j];
                    m1[1][j] = fminf(s, m1[1][j]);
                }
            }
        }
    }

    // reduce across the 16 lanes of each quad
    #pragma unroll
    for (int off = 1; off < 16; off <<= 1) {
        #pragma unroll
        for (int g = 0; g < 2; ++g)
            #pragma unroll
            for (int j = 0; j < 4; ++j) {
                const float om1 = __shfl_xor(m1[g][j], off, 64);
                const float om2 = __shfl_xor(m2[g][j], off, 64);
                const int  oidx = __shfl_xor(idx[g][j], off, 64);
                const bool better = (om1 < m1[g][j]) ||
                                    (om1 == m1[g][j] && oidx < idx[g][j]);
                m2[g][j] = fminf(fminf(m2[g][j], om2), fmaxf(m1[g][j], om1));
                m1[g][j] = better ? om1 : m1[g][j];
                idx[g][j] = better ? oidx : idx[g][j];
            }
    }

    if (col == 0) {
        #pragma unroll
        for (int g = 0; g < 2; ++g)
            #pragma unroll
            for (int j = 0; j < 4; ++j) {
                const int row = rb * 32 + g * 16 + quad * 4 + j;
                unsigned u = __float_as_uint(m1[g][j]);
                u = (u & 0x80000000u) ? ~u : (u | 0x80000000u);      // order-preserving
                const unsigned short dh =
                    __half_as_ushort(__float2half(m2[g][j] - m1[g][j]));
                pk[((size_t)cz * NROWS + row) * KSUB + k] =
                    ((unsigned long long)u << 32) |
                    ((unsigned)dh << 16) | (unsigned)idx[g][j];
            }
    }
}

// ---------------- Kernel 3: finish = merge + exact rescue + LUT output ----------------
// Any cross-split exact tie or near-tie lands below FB_TAU -> exact fp32 rescan,
// so the margin-field tie-order quirk in the packed u64 is correctness-neutral.
__global__ __launch_bounds__(256) void finish_kernel(
    const float* __restrict__ xk, const float* __restrict__ ce,
    const float* __restrict__ cnorm, const unsigned long long* __restrict__ pk,
    const float* __restrict__ W3, const float* __restrict__ b3,
    float* __restrict__ out)
{
    __shared__ int codes_s[256];
    __shared__ int wl_s[256];
    __shared__ int wcnt;
    const int t = threadIdx.x;
    const int row0 = blockIdx.x * 32;
    if (t == 0) wcnt = 0;
    __syncthreads();

    // merge 4 splits for (row, k) = (row0 + t>>3, t&7)
    {
        const int row = row0 + (t >> 3);
        const int k = t & 7;
        unsigned long long p[4];
        #pragma unroll
        for (int s = 0; s < 4; ++s)
            p[s] = pk[((size_t)s * NROWS + row) * KSUB + k];
        unsigned long long w = p[0];
        #pragma unroll
        for (int s = 1; s < 4; ++s) w = p[s] < w ? p[s] : w;
        const unsigned uw = (unsigned)(w >> 32);
        const float m1w = __uint_as_float((uw & 0x80000000u) ? (uw ^ 0x80000000u) : ~uw);
        float m2g = m1w + (float)__ushort_as_half((unsigned short)((unsigned)w >> 16));
        #pragma unroll
        for (int s = 0; s < 4; ++s) {
            if (p[s] != w) {   // splits have disjoint idx ranges -> pk values unique
                const unsigned us = (unsigned)(p[s] >> 32);
                m2g = fminf(m2g, __uint_as_float(
                    (us & 0x80000000u) ? (us ^ 0x80000000u) : ~us));
            }
        }
        codes_s[t] = (int)(w & 0xFFFFull);
        if (m2g - m1w < FB_TAU) {      // near-tie: exact fp32 rescan needed
            const int slot = atomicAdd(&wcnt, 1);
            wl_s[slot] = t;
        }
    }
    __syncthreads();

    // exact fp32 rescue, wave-per-item over the block-local worklist
    {
        const int lane = t & 63;
        const int wid = t >> 6;
        const int nitems = wcnt;
        for (int i = wid; i < nitems; i += 4) {
            const int wg = wl_s[i];
            const int row = row0 + (wg >> 3), k = wg & 7;
            float xr[DSUB];
            {
                const float* xp = &xk[((size_t)k * NROWS + row) * DSUB];
                #pragma unroll
                for (int q = 0; q < DSUB; q += 4) {
                    const float4 v = *(const float4*)&xp[q];
                    xr[q + 0] = -2.f * v.x; xr[q + 1] = -2.f * v.y;
                    xr[q + 2] = -2.f * v.z; xr[q + 3] = -2.f * v.w;
                }
            }
            float bm = 1e30f; int bi = NC;
            for (int c = lane; c < NC; c += 64) {
                const float* cp = &ce[((size_t)k * NC + c) * DSUB];
                float s = cnorm[k * NC + c];
                #pragma unroll
                for (int d = 0; d < DSUB; ++d) s = fmaf(xr[d], cp[d], s);
                if (s < bm) { bm = s; bi = c; }
            }
            #pragma unroll
            for (int off = 1; off < 64; off <<= 1) {
                const float om = __shfl_xor(bm, off, 64);
                const int  oi = __shfl_xor(bi, off, 64);
                const bool better = (om < bm) || (om == bm && oi < bi);
                bm = better ? om : bm;
                bi = better ? oi : bi;
            }
            if (lane == 0) codes_s[wg] = bi;
        }
    }
    __syncthreads();

    // output: 32 rows x 6 = 192 outputs
    if (t < 32 * OUTD) {
        const int nl = t / OUTD;
        const int o = t - nl * OUTD;
        const int n = row0 + nl;
        float acc = b3[o];
        #pragma unroll
        for (int k = 0; k < KSUB; ++k) {
            const int code = codes_s[nl * KSUB + k];
            const float* cp = &ce[((size_t)k * NC + code) * DSUB];
            const float* wp = &W3[(k * DSUB) * OUTD + o];
            #pragma unroll
            for (int d = 0; d < DSUB; ++d)
                acc = fmaf(cp[d], wp[d * OUTD], acc);
        }
        out[n * OUTD + o] = acc;
    }
}

extern "C" void kernel_launch(void* const* d_in, const int* in_sizes, int n_in,
                              void* d_out, int out_size, void* d_ws, size_t ws_size,
                              hipStream_t stream)
{
    const float* z  = (const float*)d_in[0];
    const float* W1 = (const float*)d_in[1];
    const float* b1 = (const float*)d_in[2];
    const float* W2 = (const float*)d_in[3];
    const float* b2 = (const float*)d_in[4];
    const float* ce = (const float*)d_in[5];
    const float* W3 = (const float*)d_in[6];
    const float* b3 = (const float*)d_in[7];

    char* ws = (char*)d_ws;
    float* xk    = (float*)(ws + XK_OFF);
    float* cnorm = (float*)(ws + CN_OFF);
    f16x8* B1S   = (f16x8*)(ws + B1_OFF);
    unsigned long long* pk = (unsigned long long*)(ws + PK_OFF);

    hipLaunchKernelGGL(prep_kernel, dim3(256), dim3(256), 0, stream,
                       z, W1, b1, W2, b2, ce, xk, cnorm, B1S);
    hipLaunchKernelGGL(argmin_kernel, dim3(64, 8, 4), dim3(256), 0, stream,
                       xk, B1S, cnorm, pk);
    hipLaunchKernelGGL(finish_kernel, dim3(256), dim3(256), 0, stream,
                       xk, ce, cnorm, pk, W3, b3, (float*)d_out);
}